// Round 9
// baseline (98.879 us; speedup 1.0000x reference)
//
#include <hip/hip_runtime.h>
#include <math.h>

// Problem constants
constexpr int NB  = 16;    // batch
constexpr int NH  = 50;    // history
constexpr int NS  = 512;   // signals
constexpr int ND  = 256;   // dim
constexpr int NK  = 8;     // top-k
constexpr int SM1 = NS - 1;             // 511 candidate positions
constexpr int ROWS = NH * (NK + 1) - 1; // 449 output rows per batch

// DPP-based add of a lane-permuted value (pure VALU, no LDS pipe).
template<int CTRL>
__device__ __forceinline__ float dpp_add(float v) {
    const int p = __builtin_amdgcn_update_dpp(0, __float_as_int(v), CTRL, 0xF, 0xF, true);
    return v + __int_as_float(p);
}

__device__ __forceinline__ float dpp_reduce16(float v) {
    v = dpp_add<0xB1>(v);   // quad swap-1
    v = dpp_add<0x4E>(v);   // quad swap-2
    v = dpp_add<0x141>(v);  // row_half_mirror
    v = dpp_add<0x140>(v);  // row_mirror
    return v;
}

// Non-temporal float4 load: no-allocate streaming read (nt-flagged dwordx4).
__device__ __forceinline__ float4 ntload4(const float* p) {
    typedef float f4v __attribute__((ext_vector_type(4)));
    const f4v v = __builtin_nontemporal_load((const f4v*)p);
    float4 r; r.x = v.x; r.y = v.y; r.z = v.z; r.w = v.w;
    return r;
}

// ---------------------------------------------------------------------------
// Fused kernel: one block per (b,h), 256 threads (4 waves, 16 quarter-waves).
// Phase A: query GEMV (raw, un-normalized) -> qs in LDS; 1/||q|| scalar.
// Phase B: 511 cosine scores via nt streaming (R8's proven inner loop).
// Phase C: wave-0 top-8 (+softmax) -> LDS broadcast.
// Phase D: all waves write the 9 output rows + mask + kid.
// No global workspace, no inter-kernel barriers.
// ---------------------------------------------------------------------------
__global__ __launch_bounds__(256, 8) void fused_kernel(
    const float* __restrict__ sel,     // (NB,NH,NS,ND)
    const float* __restrict__ emb,     // (NB,NH,NS,ND)
    const float* __restrict__ user,    // (NB,1,ND)
    const float* __restrict__ nrp,     // (NB,NH,ND)
    const int*   __restrict__ attn,    // (NB,NH,NS)
    const int*   __restrict__ refined, // (NB,NH,NS)
    const float* __restrict__ W,       // (ND, 2*ND) row-major
    const float* __restrict__ bal,     // (ND)
    const float* __restrict__ sep,     // (ND)
    const float* __restrict__ orde,    // (NH,1,ND)
    float* __restrict__ out_terms,     // (NB,ROWS,ND)
    float* __restrict__ out_mask,      // (NB,ROWS)
    float* __restrict__ out_kid)       // (NB,NH,NK) as float
{
    __shared__ float xs[2 * ND];   // [user(b) ; news_repr(b,h)]
    __shared__ float qs[ND];       // raw (un-normalized) query
    __shared__ float sc_s[NS];     // raw cosine scores (indexed by j)
    __shared__ float red[4];
    __shared__ float qinv_sh;
    __shared__ int   kid_sh[NK];
    __shared__ float wgt_sh[NK];

    const int bh   = blockIdx.x;
    const int b    = bh / NH, h = bh % NH;
    const int tid  = threadIdx.x;
    const int ql   = tid & 15;   // lane within quarter
    const int q    = tid >> 4;   // quarter id 0..15
    const int lane = tid & 63, wv = tid >> 6;

    // ---- Phase A: stage x, query GEMV (coalesced W rows), 1/||q|| ----
    xs[tid]      = user[(size_t)b * ND + tid];
    xs[ND + tid] = nrp[(size_t)bh * ND + tid];
    __syncthreads();

    for (int p = 0; p < 16; ++p) {
        const int d = p * 16 + q;
        const float* wrow = W + (size_t)d * (2 * ND);
        float acc = 0.f;
        #pragma unroll
        for (int i = 0; i < 8; ++i) {          // e spans 0..511
            const int e = ql * 4 + 64 * i;
            const float4 wvv = *(const float4*)(wrow + e);
            const float4 xv  = *(const float4*)(xs + e);
            acc += wvv.x * xv.x + wvv.y * xv.y + wvv.z * xv.z + wvv.w * xv.w;
        }
        acc = dpp_reduce16(acc);
        if (ql == 0) qs[d] = bal[d] + acc;
    }
    __syncthreads();

    {
        const float v = qs[tid];
        float sq = v * v;
        #pragma unroll
        for (int m = 1; m < 64; m <<= 1) sq += __shfl_xor(sq, m, 64);
        if (lane == 0) red[wv] = sq;
        __syncthreads();
        if (tid == 0)
            qinv_sh = 1.f / fmaxf(sqrtf(red[0] + red[1] + red[2] + red[3]), 1e-12f);
        __syncthreads();
    }
    const float qinv = qinv_sh;

    // ---- Phase B: scores (R8's proven nt inner loop; 32 iters) ----
    const float* base_bh = sel + (size_t)bh * NS * ND;
    #pragma unroll 2
    for (int it = 0; it < 32; ++it) {
        const int j = q + it * 16;
        const bool valid = (j < SM1);
        const int s = valid ? (j + 1) : SM1;   // safe in-bounds dummy row
        const float* row = base_bh + (size_t)s * ND;
        float dot = 0.f, nrm = 0.f;
        #pragma unroll
        for (int i = 0; i < 4; ++i) {
            const float4 v  = ntload4(row + i * 64 + ql * 4);
            const float4 qv = *(const float4*)(qs + i * 64 + ql * 4);
            dot += v.x * qv.x + v.y * qv.y + v.z * qv.z + v.w * qv.w;
            nrm += v.x * v.x + v.y * v.y + v.z * v.z + v.w * v.w;
        }
        dot = dpp_reduce16(dot);
        nrm = dpp_reduce16(nrm);
        if (valid && ql == 0)
            sc_s[j] = dot * qinv / fmaxf(sqrtf(nrm), 1e-12f);
    }
    __syncthreads();

    // ---- Phase C: wave-0 top-8 + softmax -> LDS broadcast ----
    if (wv == 0) {
        float v[8];
        #pragma unroll
        for (int t = 0; t < 8; ++t) {
            const int j = lane * 8 + t;
            float x = sc_s[j];
            if (j >= SM1)
                x = -INFINITY;
            else if (j >= NK && refined[(size_t)bh * NS + j + 1] == 0)
                x = -INFINITY;
            v[t] = x;
        }

        float topv[NK];
        int   topi[NK];
        int   myi = 0;
        #pragma unroll
        for (int k = 0; k < NK; ++k) {
            float bv = -INFINITY; int bi = 0x7fffffff;
            #pragma unroll
            for (int t = 0; t < 8; ++t)
                if (v[t] > bv) { bv = v[t]; bi = lane * 8 + t; }  // ties -> lower idx
            #pragma unroll
            for (int m = 1; m < 64; m <<= 1) {
                const float ov = __shfl_xor(bv, m, 64);
                const int   oi = __shfl_xor(bi, m, 64);
                if (ov > bv || (ov == bv && oi < bi)) { bv = ov; bi = oi; }
            }
            topv[k] = bv; topi[k] = bi;
            if (lane == k) myi = bi;
            #pragma unroll
            for (int t = 0; t < 8; ++t)
                if (lane * 8 + t == bi) v[t] = -INFINITY;
        }

        float wk[NK], ssum = 0.f;
        #pragma unroll
        for (int k = 0; k < NK; ++k) { wk[k] = expf(topv[k] - topv[0]); ssum += wk[k]; }
        const float inv = 1.f / ssum;

        if (lane == 0) {
            #pragma unroll
            for (int k = 0; k < NK; ++k) {     // static indices only
                kid_sh[k] = topi[k];
                wgt_sh[k] = wk[k] * inv;
            }
        }

        // mask + kid outputs (lane k holds myi = topi[k])
        if (lane < NK) {
            out_mask[(size_t)b * ROWS + h * (NK + 1) + lane] =
                (float)attn[(size_t)bh * NS + myi + 1];
            out_kid[(size_t)bh * NK + lane] = (float)myi;
        }
        if (lane == NK && h < NH - 1)
            out_mask[(size_t)b * ROWS + h * (NK + 1) + NK] = 1.0f;
    }
    __syncthreads();

    // ---- Phase D: output rows (wave w -> rows w, w+4, [w==0 also row 8]) ----
    const int d4 = lane * 4;
    const float4 ord4 = *(const float4*)(orde + (size_t)h * ND + d4);
    float* obase = out_terms + ((size_t)b * ROWS + h * (NK + 1)) * ND;
    for (int r = wv; r < NK + 1; r += 4) {
        if (r < NK) {
            const int s2 = kid_sh[r] + 1;
            const float4 e = *(const float4*)(emb + ((size_t)bh * NS + s2) * ND + d4);
            const float w = wgt_sh[r];
            float4 o;
            o.x = e.x * w + ord4.x;
            o.y = e.y * w + ord4.y;
            o.z = e.z * w + ord4.z;
            o.w = e.w * w + ord4.w;
            *(float4*)(obase + r * ND + d4) = o;
        } else if (h < NH - 1) {
            *(float4*)(obase + NK * ND + d4) = *(const float4*)(sep + d4);
        }
    }
}

// ---------------------------------------------------------------------------
extern "C" void kernel_launch(void* const* d_in, const int* in_sizes, int n_in,
                              void* d_out, int out_size, void* d_ws, size_t ws_size,
                              hipStream_t stream) {
    const float* sel   = (const float*)d_in[0];
    const float* emb   = (const float*)d_in[1];
    const float* user  = (const float*)d_in[2];
    const float* nrp   = (const float*)d_in[3];
    const int*   attn  = (const int*)d_in[4];
    const int*   refin = (const int*)d_in[5];
    const float* W     = (const float*)d_in[6];
    const float* bal   = (const float*)d_in[7];
    const float* sep   = (const float*)d_in[8];
    const float* orde  = (const float*)d_in[9];

    float* out_terms = (float*)d_out;
    float* out_mask  = out_terms + (size_t)NB * ROWS * ND;
    float* out_kid   = out_mask + (size_t)NB * ROWS;

    fused_kernel<<<NB * NH, 256, 0, stream>>>(sel, emb, user, nrp, attn, refin,
                                              W, bal, sep, orde,
                                              out_terms, out_mask, out_kid);
}

// Round 10
// 96.799 us; speedup vs baseline: 1.0215x; 1.0215x over previous
//
#include <hip/hip_runtime.h>
#include <math.h>

// Problem constants
constexpr int NB  = 16;    // batch
constexpr int NH  = 50;    // history
constexpr int NS  = 512;   // signals
constexpr int ND  = 256;   // dim
constexpr int NK  = 8;     // top-k
constexpr int SM1 = NS - 1;             // 511 candidate positions
constexpr int ROWS = NH * (NK + 1) - 1; // 449 output rows per batch
constexpr int HB  = 5;     // h-values per block in query kernel

// DPP-based add of a lane-permuted value (pure VALU, no LDS pipe).
template<int CTRL>
__device__ __forceinline__ float dpp_add(float v) {
    const int p = __builtin_amdgcn_update_dpp(0, __float_as_int(v), CTRL, 0xF, 0xF, true);
    return v + __int_as_float(p);
}

__device__ __forceinline__ float dpp_reduce16(float v) {
    v = dpp_add<0xB1>(v);   // quad swap-1
    v = dpp_add<0x4E>(v);   // quad swap-2
    v = dpp_add<0x141>(v);  // row_half_mirror
    v = dpp_add<0x140>(v);  // row_mirror
    return v;
}

// Non-temporal float4 load: no-allocate streaming read (nt-flagged dwordx4).
__device__ __forceinline__ float4 ntload4(const float* p) {
    typedef float f4v __attribute__((ext_vector_type(4)));
    const f4v v = __builtin_nontemporal_load((const f4v*)p);
    float4 r; r.x = v.x; r.y = v.y; r.z = v.z; r.w = v.w;
    return r;
}

// ---------------------------------------------------------------------------
// Kernel 1 (unchanged from R5): coalesced-W query GEMV, 160 blocks.
// ---------------------------------------------------------------------------
__global__ __launch_bounds__(256) void query_kernel(
    const float* __restrict__ user,      // (NB, 1, ND)
    const float* __restrict__ news_repr, // (NB, NH, ND)
    const float* __restrict__ W,         // (ND, 2*ND) row-major
    const float* __restrict__ bal,       // (ND)
    float* __restrict__ qn)              // (NB*NH, ND)
{
    __shared__ float us[ND];
    __shared__ float nr[HB][ND];
    __shared__ float qv_s[HB][ND];
    __shared__ float red[4];

    const int blk = blockIdx.x;
    const int b   = blk / (NH / HB);
    const int h0  = (blk % (NH / HB)) * HB;
    const int tid = threadIdx.x;
    const int ql  = tid & 15;   // lane within quarter
    const int q   = tid >> 4;   // quarter id 0..15

    us[tid] = user[b * ND + tid];
    #pragma unroll
    for (int i = 0; i < HB; ++i)
        nr[i][tid] = news_repr[((size_t)(b * NH + h0 + i)) * ND + tid];
    __syncthreads();

    for (int p = 0; p < 16; ++p) {
        const int d = p * 16 + q;
        const float* wrow = W + (size_t)d * (2 * ND);
        float pu = 0.f;
        float pa[HB];
        #pragma unroll
        for (int j = 0; j < HB; ++j) pa[j] = 0.f;

        #pragma unroll
        for (int i = 0; i < 4; ++i) {        // user half: e = ql*4 + 64*i
            const int e = ql * 4 + 64 * i;
            const float4 wv = *(const float4*)(wrow + e);
            const float4 xv = *(const float4*)(us + e);
            pu += wv.x * xv.x + wv.y * xv.y + wv.z * xv.z + wv.w * xv.w;
        }
        #pragma unroll
        for (int i = 0; i < 4; ++i) {        // repr half
            const int e = ql * 4 + 64 * i;
            const float4 wv = *(const float4*)(wrow + ND + e);
            #pragma unroll
            for (int j = 0; j < HB; ++j) {
                const float4 xv = *(const float4*)(&nr[j][e]);
                pa[j] += wv.x * xv.x + wv.y * xv.y + wv.z * xv.z + wv.w * xv.w;
            }
        }

        pu = dpp_reduce16(pu);
        #pragma unroll
        for (int j = 0; j < HB; ++j) pa[j] = dpp_reduce16(pa[j]);

        if (ql == 0) {
            const float base = bal[d] + pu;
            #pragma unroll
            for (int j = 0; j < HB; ++j) qv_s[j][d] = base + pa[j];
        }
    }
    __syncthreads();

    const int lane = tid & 63, wv_ = tid >> 6;
    for (int j = 0; j < HB; ++j) {
        const float v = qv_s[j][tid];
        float sq = v * v;
        #pragma unroll
        for (int m = 1; m < 64; m <<= 1) sq += __shfl_xor(sq, m, 64);
        if (lane == 0) red[wv_] = sq;
        __syncthreads();
        const float tot = red[0] + red[1] + red[2] + red[3];
        __syncthreads();
        qn[((size_t)(b * NH + h0 + j)) * ND + tid] = v / fmaxf(sqrtf(tot), 1e-12f);
    }
}

// ---------------------------------------------------------------------------
// Kernel 2 (FUSED score+topk+output): one block per (b,h), 256 threads.
// Phase B: R8's exact nt inner loop, 32 iters, scores -> LDS (no scw global).
// Phase C: wave-0 top-8 + softmax (R9-proven) -> LDS broadcast + mask/kid.
// Phase D: all 4 waves write the 9 output rows.
// ---------------------------------------------------------------------------
__global__ __launch_bounds__(256, 8) void score_topk_kernel(
    const float* __restrict__ sel,     // (NB,NH,NS,ND)
    const float* __restrict__ emb,     // (NB,NH,NS,ND)
    const int*   __restrict__ attn,    // (NB,NH,NS)
    const int*   __restrict__ refined, // (NB,NH,NS)
    const float* __restrict__ qn,      // (NB*NH, ND) normalized queries
    const float* __restrict__ sep,     // (ND)
    const float* __restrict__ orde,    // (NH,1,ND)
    float* __restrict__ out_terms,     // (NB,ROWS,ND)
    float* __restrict__ out_mask,      // (NB,ROWS)
    float* __restrict__ out_kid)       // (NB,NH,NK) as float
{
    __shared__ float qs[ND];
    __shared__ float sc_s[NS];
    __shared__ int   kid_sh[NK];
    __shared__ float wgt_sh[NK];

    const int bh   = blockIdx.x;
    const int b    = bh / NH, h = bh % NH;
    const int tid  = threadIdx.x;
    const int ql   = tid & 15;   // lane within quarter
    const int q    = tid >> 4;   // quarter id 0..15
    const int lane = tid & 63, wv = tid >> 6;

    qs[tid] = qn[(size_t)bh * ND + tid];
    __syncthreads();

    // ---- Phase B: scores (R8's proven nt inner loop; 32 iters) ----
    const float* base_bh = sel + (size_t)bh * NS * ND;
    #pragma unroll 2
    for (int it = 0; it < 32; ++it) {
        const int j = q + it * 16;
        const bool valid = (j < SM1);
        const int s = valid ? (j + 1) : SM1;   // safe in-bounds dummy row
        const float* row = base_bh + (size_t)s * ND;
        float dot = 0.f, nrm = 0.f;
        #pragma unroll
        for (int i = 0; i < 4; ++i) {
            const float4 v  = ntload4(row + i * 64 + ql * 4);
            const float4 qv = *(const float4*)(qs + i * 64 + ql * 4);
            dot += v.x * qv.x + v.y * qv.y + v.z * qv.z + v.w * qv.w;
            nrm += v.x * v.x + v.y * v.y + v.z * v.z + v.w * v.w;
        }
        dot = dpp_reduce16(dot);
        nrm = dpp_reduce16(nrm);
        if (valid && ql == 0)
            sc_s[j] = dot / fmaxf(sqrtf(nrm), 1e-12f);
    }
    __syncthreads();

    // ---- Phase C: wave-0 top-8 + softmax -> LDS broadcast ----
    if (wv == 0) {
        float v[8];
        #pragma unroll
        for (int t = 0; t < 8; ++t) {
            const int j = lane * 8 + t;
            float x = sc_s[j];
            if (j >= SM1)
                x = -INFINITY;
            else if (j >= NK && refined[(size_t)bh * NS + j + 1] == 0)
                x = -INFINITY;
            v[t] = x;
        }

        float topv[NK];
        int   topi[NK];
        int   myi = 0;
        #pragma unroll
        for (int k = 0; k < NK; ++k) {
            float bv = -INFINITY; int bi = 0x7fffffff;
            #pragma unroll
            for (int t = 0; t < 8; ++t)
                if (v[t] > bv) { bv = v[t]; bi = lane * 8 + t; }  // ties -> lower idx
            #pragma unroll
            for (int m = 1; m < 64; m <<= 1) {
                const float ov = __shfl_xor(bv, m, 64);
                const int   oi = __shfl_xor(bi, m, 64);
                if (ov > bv || (ov == bv && oi < bi)) { bv = ov; bi = oi; }
            }
            topv[k] = bv; topi[k] = bi;
            if (lane == k) myi = bi;
            #pragma unroll
            for (int t = 0; t < 8; ++t)
                if (lane * 8 + t == bi) v[t] = -INFINITY;
        }

        float wk[NK], ssum = 0.f;
        #pragma unroll
        for (int k = 0; k < NK; ++k) { wk[k] = expf(topv[k] - topv[0]); ssum += wk[k]; }
        const float inv = 1.f / ssum;

        if (lane == 0) {
            #pragma unroll
            for (int k = 0; k < NK; ++k) {     // static indices only
                kid_sh[k] = topi[k];
                wgt_sh[k] = wk[k] * inv;
            }
        }

        if (lane < NK) {
            out_mask[(size_t)b * ROWS + h * (NK + 1) + lane] =
                (float)attn[(size_t)bh * NS + myi + 1];
            out_kid[(size_t)bh * NK + lane] = (float)myi;
        }
        if (lane == NK && h < NH - 1)
            out_mask[(size_t)b * ROWS + h * (NK + 1) + NK] = 1.0f;
    }
    __syncthreads();

    // ---- Phase D: output rows (wave w -> rows w, w+4, [w==0 also row 8]) ----
    const int d4 = lane * 4;
    const float4 ord4 = *(const float4*)(orde + (size_t)h * ND + d4);
    float* obase = out_terms + ((size_t)b * ROWS + h * (NK + 1)) * ND;
    for (int r = wv; r < NK + 1; r += 4) {
        if (r < NK) {
            const int s2 = kid_sh[r] + 1;
            const float4 e = *(const float4*)(emb + ((size_t)bh * NS + s2) * ND + d4);
            const float w = wgt_sh[r];
            float4 o;
            o.x = e.x * w + ord4.x;
            o.y = e.y * w + ord4.y;
            o.z = e.z * w + ord4.z;
            o.w = e.w * w + ord4.w;
            *(float4*)(obase + r * ND + d4) = o;
        } else if (h < NH - 1) {
            *(float4*)(obase + NK * ND + d4) = *(const float4*)(sep + d4);
        }
    }
}

// ---------------------------------------------------------------------------
extern "C" void kernel_launch(void* const* d_in, const int* in_sizes, int n_in,
                              void* d_out, int out_size, void* d_ws, size_t ws_size,
                              hipStream_t stream) {
    const float* sel   = (const float*)d_in[0];
    const float* emb   = (const float*)d_in[1];
    const float* user  = (const float*)d_in[2];
    const float* nrp   = (const float*)d_in[3];
    const int*   attn  = (const int*)d_in[4];
    const int*   refin = (const int*)d_in[5];
    const float* W     = (const float*)d_in[6];
    const float* bal   = (const float*)d_in[7];
    const float* sep   = (const float*)d_in[8];
    const float* orde  = (const float*)d_in[9];

    float* qn = (float*)d_ws;   // NB*NH*ND floats (800 KB)

    float* out_terms = (float*)d_out;
    float* out_mask  = out_terms + (size_t)NB * ROWS * ND;
    float* out_kid   = out_mask + (size_t)NB * ROWS;

    query_kernel<<<NB * (NH / HB), 256, 0, stream>>>(user, nrp, W, bal, qn);
    score_topk_kernel<<<NB * NH, 256, 0, stream>>>(sel, emb, attn, refin, qn,
                                                   sep, orde,
                                                   out_terms, out_mask, out_kid);
}

// Round 11
// 94.122 us; speedup vs baseline: 1.0505x; 1.0284x over previous
//
#include <hip/hip_runtime.h>
#include <math.h>

// Problem constants
constexpr int NB  = 16;    // batch
constexpr int NH  = 50;    // history
constexpr int NS  = 512;   // signals
constexpr int ND  = 256;   // dim
constexpr int NK  = 8;     // top-k
constexpr int SM1 = NS - 1;             // 511 candidate positions
constexpr int ROWS = NH * (NK + 1) - 1; // 449 output rows per batch
constexpr int HB  = 5;     // h-values per block in query kernel
constexpr int CHUNKS = 2;  // score chunks per (b,h)  [R11: 4 -> 2]
constexpr int RPC = 256;   // rows per chunk (last chunk covers 255 valid)

// DPP-based add of a lane-permuted value (pure VALU, no LDS pipe).
template<int CTRL>
__device__ __forceinline__ float dpp_add(float v) {
    const int p = __builtin_amdgcn_update_dpp(0, __float_as_int(v), CTRL, 0xF, 0xF, true);
    return v + __int_as_float(p);
}

__device__ __forceinline__ float dpp_reduce16(float v) {
    v = dpp_add<0xB1>(v);   // quad swap-1
    v = dpp_add<0x4E>(v);   // quad swap-2
    v = dpp_add<0x141>(v);  // row_half_mirror
    v = dpp_add<0x140>(v);  // row_mirror
    return v;
}

// Non-temporal float4 load: no-allocate streaming read (nt-flagged dwordx4).
__device__ __forceinline__ float4 ntload4(const float* p) {
    typedef float f4v __attribute__((ext_vector_type(4)));
    const f4v v = __builtin_nontemporal_load((const f4v*)p);
    float4 r; r.x = v.x; r.y = v.y; r.z = v.z; r.w = v.w;
    return r;
}

// ---------------------------------------------------------------------------
// Kernel 1 (unchanged from R5): coalesced-W query GEMV, 160 blocks.
// ---------------------------------------------------------------------------
__global__ __launch_bounds__(256) void query_kernel(
    const float* __restrict__ user,      // (NB, 1, ND)
    const float* __restrict__ news_repr, // (NB, NH, ND)
    const float* __restrict__ W,         // (ND, 2*ND) row-major
    const float* __restrict__ bal,       // (ND)
    float* __restrict__ qn)              // (NB*NH, ND)
{
    __shared__ float us[ND];
    __shared__ float nr[HB][ND];
    __shared__ float qv_s[HB][ND];
    __shared__ float red[4];

    const int blk = blockIdx.x;
    const int b   = blk / (NH / HB);
    const int h0  = (blk % (NH / HB)) * HB;
    const int tid = threadIdx.x;
    const int ql  = tid & 15;   // lane within quarter
    const int q   = tid >> 4;   // quarter id 0..15

    us[tid] = user[b * ND + tid];
    #pragma unroll
    for (int i = 0; i < HB; ++i)
        nr[i][tid] = news_repr[((size_t)(b * NH + h0 + i)) * ND + tid];
    __syncthreads();

    for (int p = 0; p < 16; ++p) {
        const int d = p * 16 + q;
        const float* wrow = W + (size_t)d * (2 * ND);
        float pu = 0.f;
        float pa[HB];
        #pragma unroll
        for (int j = 0; j < HB; ++j) pa[j] = 0.f;

        #pragma unroll
        for (int i = 0; i < 4; ++i) {        // user half: e = ql*4 + 64*i
            const int e = ql * 4 + 64 * i;
            const float4 wv = *(const float4*)(wrow + e);
            const float4 xv = *(const float4*)(us + e);
            pu += wv.x * xv.x + wv.y * xv.y + wv.z * xv.z + wv.w * xv.w;
        }
        #pragma unroll
        for (int i = 0; i < 4; ++i) {        // repr half
            const int e = ql * 4 + 64 * i;
            const float4 wv = *(const float4*)(wrow + ND + e);
            #pragma unroll
            for (int j = 0; j < HB; ++j) {
                const float4 xv = *(const float4*)(&nr[j][e]);
                pa[j] += wv.x * xv.x + wv.y * xv.y + wv.z * xv.z + wv.w * xv.w;
            }
        }

        pu = dpp_reduce16(pu);
        #pragma unroll
        for (int j = 0; j < HB; ++j) pa[j] = dpp_reduce16(pa[j]);

        if (ql == 0) {
            const float base = bal[d] + pu;
            #pragma unroll
            for (int j = 0; j < HB; ++j) qv_s[j][d] = base + pa[j];
        }
    }
    __syncthreads();

    const int lane = tid & 63, wv_ = tid >> 6;
    for (int j = 0; j < HB; ++j) {
        const float v = qv_s[j][tid];
        float sq = v * v;
        #pragma unroll
        for (int m = 1; m < 64; m <<= 1) sq += __shfl_xor(sq, m, 64);
        if (lane == 0) red[wv_] = sq;
        __syncthreads();
        const float tot = red[0] + red[1] + red[2] + red[3];
        __syncthreads();
        qn[((size_t)(b * NH + h0 + j)) * ND + tid] = v / fmaxf(sqrtf(tot), 1e-12f);
    }
}

// ---------------------------------------------------------------------------
// Kernel 2: scores (R7 structure; CHUNKS=2 -> 1600 blocks, all co-resident).
// grid = NB*NH*CHUNKS blocks, 256 threads; quarter-wave per row; nt loads.
// ---------------------------------------------------------------------------
__global__ __launch_bounds__(256) void score_kernel(
    const float* __restrict__ sel,  // (NB,NH,NS,ND)
    const float* __restrict__ qn,   // (NB*NH, ND)
    float* __restrict__ scw)        // (NB*NH, NS)
{
    const int blk   = blockIdx.x;
    const int bh    = blk >> 1;     // / CHUNKS
    const int chunk = blk & (CHUNKS - 1);
    const int j0    = chunk * RPC;
    const int tid   = threadIdx.x;
    const int ql    = tid & 15;     // lane within quarter
    const int q     = tid >> 4;     // quarter id 0..15

    float4 qf[4];
    #pragma unroll
    for (int i = 0; i < 4; ++i)
        qf[i] = *(const float4*)(qn + (size_t)bh * ND + i * 64 + ql * 4);

    const float* base_bh = sel + (size_t)bh * NS * ND;

    #pragma unroll 2
    for (int it = 0; it < RPC / 16; ++it) {
        const int j = j0 + q + it * 16;
        const bool valid = (j < SM1);
        const int s = valid ? (j + 1) : SM1;   // safe in-bounds row for the dummy
        const float* row = base_bh + (size_t)s * ND;
        float dot = 0.f, nrm = 0.f;
        #pragma unroll
        for (int i = 0; i < 4; ++i) {
            const float4 v = ntload4(row + i * 64 + ql * 4);
            dot += v.x * qf[i].x + v.y * qf[i].y + v.z * qf[i].z + v.w * qf[i].w;
            nrm += v.x * v.x + v.y * v.y + v.z * v.z + v.w * v.w;
        }
        dot = dpp_reduce16(dot);
        nrm = dpp_reduce16(nrm);

        if (valid && ql == 0)
            scw[(size_t)bh * NS + j] = dot / fmaxf(sqrtf(nrm), 1e-12f);
    }
}

// ---------------------------------------------------------------------------
// Kernel 3 (unchanged from R4): one wave per (b,h). grid = NB*NH, 64 threads.
// ---------------------------------------------------------------------------
__global__ __launch_bounds__(64) void topk_out_kernel(
    const float* __restrict__ emb,     // (NB,NH,NS,ND)
    const int*   __restrict__ attn,    // (NB,NH,NS)
    const int*   __restrict__ refined, // (NB,NH,NS)
    const float* __restrict__ scw,     // (NB*NH, NS) raw scores
    const float* __restrict__ sep,     // (ND)
    const float* __restrict__ orde,    // (NH, 1, ND)
    float* __restrict__ out_terms,     // (NB, ROWS, ND)
    float* __restrict__ out_mask,      // (NB, ROWS)
    float* __restrict__ out_kid)       // (NB, NH, NK) as float
{
    const int bh   = blockIdx.x;
    const int b    = bh / NH, h = bh % NH;
    const int lane = threadIdx.x;

    float v[8];
    {
        const float4 a = *(const float4*)(scw + (size_t)bh * NS + lane * 8);
        const float4 c = *(const float4*)(scw + (size_t)bh * NS + lane * 8 + 4);
        v[0] = a.x; v[1] = a.y; v[2] = a.z; v[3] = a.w;
        v[4] = c.x; v[5] = c.y; v[6] = c.z; v[7] = c.w;
    }
    #pragma unroll
    for (int t = 0; t < 8; ++t) {
        const int j = lane * 8 + t;
        if (j >= SM1)
            v[t] = -INFINITY;
        else if (j >= NK && refined[(size_t)bh * NS + j + 1] == 0)
            v[t] = -INFINITY;
    }

    float topv[NK];
    int   topi[NK];
    int   myi = 0;
    #pragma unroll
    for (int k = 0; k < NK; ++k) {
        float bv = -INFINITY; int bi = 0x7fffffff;
        #pragma unroll
        for (int t = 0; t < 8; ++t)
            if (v[t] > bv) { bv = v[t]; bi = lane * 8 + t; }  // ties -> lower idx
        #pragma unroll
        for (int m = 1; m < 64; m <<= 1) {
            const float ov = __shfl_xor(bv, m, 64);
            const int   oi = __shfl_xor(bi, m, 64);
            if (ov > bv || (ov == bv && oi < bi)) { bv = ov; bi = oi; }
        }
        topv[k] = bv; topi[k] = bi;
        if (lane == k) myi = bi;
        #pragma unroll
        for (int t = 0; t < 8; ++t)
            if (lane * 8 + t == bi) v[t] = -INFINITY;
    }

    float wk[NK], ssum = 0.f;
    #pragma unroll
    for (int k = 0; k < NK; ++k) { wk[k] = expf(topv[k] - topv[0]); ssum += wk[k]; }
    const float inv = 1.f / ssum;

    const int d4 = lane * 4;
    const float4 ord4 = *(const float4*)(orde + (size_t)h * ND + d4);
    float* obase = out_terms + ((size_t)b * ROWS + h * (NK + 1)) * ND;
    #pragma unroll
    for (int k = 0; k < NK; ++k) {
        const int s = topi[k] + 1;
        const float4 e = *(const float4*)(emb + ((size_t)bh * NS + s) * ND + d4);
        const float w = wk[k] * inv;
        float4 o;
        o.x = e.x * w + ord4.x;
        o.y = e.y * w + ord4.y;
        o.z = e.z * w + ord4.z;
        o.w = e.w * w + ord4.w;
        *(float4*)(obase + k * ND + d4) = o;
    }
    const bool has_sep = h < NH - 1;
    if (has_sep)
        *(float4*)(obase + NK * ND + d4) = *(const float4*)(sep + d4);

    if (lane < NK) {
        out_mask[(size_t)b * ROWS + h * (NK + 1) + lane] =
            (float)attn[(size_t)bh * NS + myi + 1];
        out_kid[(size_t)bh * NK + lane] = (float)myi;
    }
    if (lane == NK && has_sep)
        out_mask[(size_t)b * ROWS + h * (NK + 1) + NK] = 1.0f;
}

// ---------------------------------------------------------------------------
extern "C" void kernel_launch(void* const* d_in, const int* in_sizes, int n_in,
                              void* d_out, int out_size, void* d_ws, size_t ws_size,
                              hipStream_t stream) {
    const float* sel   = (const float*)d_in[0];
    const float* emb   = (const float*)d_in[1];
    const float* user  = (const float*)d_in[2];
    const float* nrp   = (const float*)d_in[3];
    const int*   attn  = (const int*)d_in[4];
    const int*   refin = (const int*)d_in[5];
    const float* W     = (const float*)d_in[6];
    const float* bal   = (const float*)d_in[7];
    const float* sep   = (const float*)d_in[8];
    const float* orde  = (const float*)d_in[9];

    float* qn  = (float*)d_ws;                       // NB*NH*ND floats (800 KB)
    float* scw = qn + (size_t)NB * NH * ND;          // NB*NH*NS floats (1.6 MB)

    float* out_terms = (float*)d_out;
    float* out_mask  = out_terms + (size_t)NB * ROWS * ND;
    float* out_kid   = out_mask + (size_t)NB * ROWS;

    query_kernel<<<NB * (NH / HB), 256, 0, stream>>>(user, nrp, W, bal, qn);
    score_kernel<<<NB * NH * CHUNKS, 256, 0, stream>>>(sel, qn, scw);
    topk_out_kernel<<<NB * NH, 64, 0, stream>>>(emb, attn, refin, scw, sep, orde,
                                                out_terms, out_mask, out_kid);
}

// Round 12
// 93.471 us; speedup vs baseline: 1.0579x; 1.0070x over previous
//
#include <hip/hip_runtime.h>
#include <math.h>

// Problem constants
constexpr int NB  = 16;    // batch
constexpr int NH  = 50;    // history
constexpr int NS  = 512;   // signals
constexpr int ND  = 256;   // dim
constexpr int NK  = 8;     // top-k
constexpr int SM1 = NS - 1;             // 511 candidate positions
constexpr int ROWS = NH * (NK + 1) - 1; // 449 output rows per batch
constexpr int HB  = 5;     // h-values per block in query kernel
constexpr int CHUNKS = 4;  // score chunks per (b,h)
constexpr int RPC = 128;   // rows per chunk (last chunk covers 127 valid)

// DPP-based add of a lane-permuted value (pure VALU, no LDS pipe).
template<int CTRL>
__device__ __forceinline__ float dpp_add(float v) {
    const int p = __builtin_amdgcn_update_dpp(0, __float_as_int(v), CTRL, 0xF, 0xF, true);
    return v + __int_as_float(p);
}

__device__ __forceinline__ float dpp_reduce16(float v) {
    v = dpp_add<0xB1>(v);   // quad swap-1
    v = dpp_add<0x4E>(v);   // quad swap-2
    v = dpp_add<0x141>(v);  // row_half_mirror
    v = dpp_add<0x140>(v);  // row_mirror
    return v;
}

// Non-temporal float4 load: no-allocate streaming read (nt-flagged dwordx4).
// sel is read exactly once -> cache-bypass is free and avoids L2/L3
// allocation churn (the R7 discovery: +23 us).
__device__ __forceinline__ float4 ntload4(const float* p) {
    typedef float f4v __attribute__((ext_vector_type(4)));
    const f4v v = __builtin_nontemporal_load((const f4v*)p);
    float4 r; r.x = v.x; r.y = v.y; r.z = v.z; r.w = v.w;
    return r;
}

// ---------------------------------------------------------------------------
// Kernel 1: coalesced-W query GEMV, 160 blocks, 256 threads.
// Quarter-wave per output dim; W rows read contiguously; DPP reduce;
// block-wide L2 normalize.
// ---------------------------------------------------------------------------
__global__ __launch_bounds__(256) void query_kernel(
    const float* __restrict__ user,      // (NB, 1, ND)
    const float* __restrict__ news_repr, // (NB, NH, ND)
    const float* __restrict__ W,         // (ND, 2*ND) row-major
    const float* __restrict__ bal,       // (ND)
    float* __restrict__ qn)              // (NB*NH, ND)
{
    __shared__ float us[ND];
    __shared__ float nr[HB][ND];
    __shared__ float qv_s[HB][ND];
    __shared__ float red[4];

    const int blk = blockIdx.x;
    const int b   = blk / (NH / HB);
    const int h0  = (blk % (NH / HB)) * HB;
    const int tid = threadIdx.x;
    const int ql  = tid & 15;   // lane within quarter
    const int q   = tid >> 4;   // quarter id 0..15

    us[tid] = user[b * ND + tid];
    #pragma unroll
    for (int i = 0; i < HB; ++i)
        nr[i][tid] = news_repr[((size_t)(b * NH + h0 + i)) * ND + tid];
    __syncthreads();

    for (int p = 0; p < 16; ++p) {
        const int d = p * 16 + q;
        const float* wrow = W + (size_t)d * (2 * ND);
        float pu = 0.f;
        float pa[HB];
        #pragma unroll
        for (int j = 0; j < HB; ++j) pa[j] = 0.f;

        #pragma unroll
        for (int i = 0; i < 4; ++i) {        // user half: e = ql*4 + 64*i
            const int e = ql * 4 + 64 * i;
            const float4 wv = *(const float4*)(wrow + e);
            const float4 xv = *(const float4*)(us + e);
            pu += wv.x * xv.x + wv.y * xv.y + wv.z * xv.z + wv.w * xv.w;
        }
        #pragma unroll
        for (int i = 0; i < 4; ++i) {        // repr half
            const int e = ql * 4 + 64 * i;
            const float4 wv = *(const float4*)(wrow + ND + e);
            #pragma unroll
            for (int j = 0; j < HB; ++j) {
                const float4 xv = *(const float4*)(&nr[j][e]);
                pa[j] += wv.x * xv.x + wv.y * xv.y + wv.z * xv.z + wv.w * xv.w;
            }
        }

        pu = dpp_reduce16(pu);
        #pragma unroll
        for (int j = 0; j < HB; ++j) pa[j] = dpp_reduce16(pa[j]);

        if (ql == 0) {
            const float base = bal[d] + pu;
            #pragma unroll
            for (int j = 0; j < HB; ++j) qv_s[j][d] = base + pa[j];
        }
    }
    __syncthreads();

    const int lane = tid & 63, wv_ = tid >> 6;
    for (int j = 0; j < HB; ++j) {
        const float v = qv_s[j][tid];
        float sq = v * v;
        #pragma unroll
        for (int m = 1; m < 64; m <<= 1) sq += __shfl_xor(sq, m, 64);
        if (lane == 0) red[wv_] = sq;
        __syncthreads();
        const float tot = red[0] + red[1] + red[2] + red[3];
        __syncthreads();
        qn[((size_t)(b * NH + h0 + j)) * ND + tid] = v / fmaxf(sqrtf(tot), 1e-12f);
    }
}

// ---------------------------------------------------------------------------
// Kernel 2: scores. grid = NB*NH*CHUNKS (3200) blocks, 256 threads.
// Quarter-wave per candidate row; NON-TEMPORAL sel loads (no L2/L3
// allocation churn); DPP reduce; uniform trip count (j=511 -> dummy row,
// store skipped).
// ---------------------------------------------------------------------------
__global__ __launch_bounds__(256) void score_kernel(
    const float* __restrict__ sel,  // (NB,NH,NS,ND)
    const float* __restrict__ qn,   // (NB*NH, ND)
    float* __restrict__ scw)        // (NB*NH, NS)
{
    const int blk   = blockIdx.x;
    const int bh    = blk >> 2;     // / CHUNKS
    const int chunk = blk & (CHUNKS - 1);
    const int j0    = chunk * RPC;
    const int tid   = threadIdx.x;
    const int ql    = tid & 15;     // lane within quarter
    const int q     = tid >> 4;     // quarter id 0..15

    float4 qf[4];
    #pragma unroll
    for (int i = 0; i < 4; ++i)
        qf[i] = *(const float4*)(qn + (size_t)bh * ND + i * 64 + ql * 4);

    const float* base_bh = sel + (size_t)bh * NS * ND;

    #pragma unroll 2
    for (int it = 0; it < 8; ++it) {
        const int j = j0 + q + it * 16;
        const bool valid = (j < SM1);
        const int s = valid ? (j + 1) : SM1;   // safe in-bounds row for the dummy
        const float* row = base_bh + (size_t)s * ND;
        float dot = 0.f, nrm = 0.f;
        #pragma unroll
        for (int i = 0; i < 4; ++i) {
            const float4 v = ntload4(row + i * 64 + ql * 4);
            dot += v.x * qf[i].x + v.y * qf[i].y + v.z * qf[i].z + v.w * qf[i].w;
            nrm += v.x * v.x + v.y * v.y + v.z * v.z + v.w * v.w;
        }
        dot = dpp_reduce16(dot);
        nrm = dpp_reduce16(nrm);

        if (valid && ql == 0)
            scw[(size_t)bh * NS + j] = dot / fmaxf(sqrtf(nrm), 1e-12f);
    }
}

// ---------------------------------------------------------------------------
// Kernel 3: one wave per (b,h). grid = NB*NH blocks, 64 threads. No LDS, no
// __syncthreads. Top-8 in registers (jax tie-break: equal value -> lower
// index), softmax, gather+scale+order, sep/mask/kid.
// ---------------------------------------------------------------------------
__global__ __launch_bounds__(64) void topk_out_kernel(
    const float* __restrict__ emb,     // (NB,NH,NS,ND)
    const int*   __restrict__ attn,    // (NB,NH,NS)
    const int*   __restrict__ refined, // (NB,NH,NS)
    const float* __restrict__ scw,     // (NB*NH, NS) raw scores
    const float* __restrict__ sep,     // (ND)
    const float* __restrict__ orde,    // (NH, 1, ND)
    float* __restrict__ out_terms,     // (NB, ROWS, ND)
    float* __restrict__ out_mask,      // (NB, ROWS)
    float* __restrict__ out_kid)       // (NB, NH, NK) as float
{
    const int bh   = blockIdx.x;
    const int b    = bh / NH, h = bh % NH;
    const int lane = threadIdx.x;

    float v[8];
    {
        const float4 a = *(const float4*)(scw + (size_t)bh * NS + lane * 8);
        const float4 c = *(const float4*)(scw + (size_t)bh * NS + lane * 8 + 4);
        v[0] = a.x; v[1] = a.y; v[2] = a.z; v[3] = a.w;
        v[4] = c.x; v[5] = c.y; v[6] = c.z; v[7] = c.w;
    }
    #pragma unroll
    for (int t = 0; t < 8; ++t) {
        const int j = lane * 8 + t;
        if (j >= SM1)
            v[t] = -INFINITY;
        else if (j >= NK && refined[(size_t)bh * NS + j + 1] == 0)
            v[t] = -INFINITY;
    }

    float topv[NK];
    int   topi[NK];
    int   myi = 0;
    #pragma unroll
    for (int k = 0; k < NK; ++k) {
        float bv = -INFINITY; int bi = 0x7fffffff;
        #pragma unroll
        for (int t = 0; t < 8; ++t)
            if (v[t] > bv) { bv = v[t]; bi = lane * 8 + t; }  // ties -> lower idx
        #pragma unroll
        for (int m = 1; m < 64; m <<= 1) {
            const float ov = __shfl_xor(bv, m, 64);
            const int   oi = __shfl_xor(bi, m, 64);
            if (ov > bv || (ov == bv && oi < bi)) { bv = ov; bi = oi; }
        }
        topv[k] = bv; topi[k] = bi;
        if (lane == k) myi = bi;
        #pragma unroll
        for (int t = 0; t < 8; ++t)
            if (lane * 8 + t == bi) v[t] = -INFINITY;
    }

    float wk[NK], ssum = 0.f;
    #pragma unroll
    for (int k = 0; k < NK; ++k) { wk[k] = expf(topv[k] - topv[0]); ssum += wk[k]; }
    const float inv = 1.f / ssum;

    const int d4 = lane * 4;
    const float4 ord4 = *(const float4*)(orde + (size_t)h * ND + d4);
    float* obase = out_terms + ((size_t)b * ROWS + h * (NK + 1)) * ND;
    #pragma unroll
    for (int k = 0; k < NK; ++k) {
        const int s = topi[k] + 1;
        const float4 e = *(const float4*)(emb + ((size_t)bh * NS + s) * ND + d4);
        const float w = wk[k] * inv;
        float4 o;
        o.x = e.x * w + ord4.x;
        o.y = e.y * w + ord4.y;
        o.z = e.z * w + ord4.z;
        o.w = e.w * w + ord4.w;
        *(float4*)(obase + k * ND + d4) = o;
    }
    const bool has_sep = h < NH - 1;
    if (has_sep)
        *(float4*)(obase + NK * ND + d4) = *(const float4*)(sep + d4);

    if (lane < NK) {
        out_mask[(size_t)b * ROWS + h * (NK + 1) + lane] =
            (float)attn[(size_t)bh * NS + myi + 1];
        out_kid[(size_t)bh * NK + lane] = (float)myi;
    }
    if (lane == NK && has_sep)
        out_mask[(size_t)b * ROWS + h * (NK + 1) + NK] = 1.0f;
}

// ---------------------------------------------------------------------------
extern "C" void kernel_launch(void* const* d_in, const int* in_sizes, int n_in,
                              void* d_out, int out_size, void* d_ws, size_t ws_size,
                              hipStream_t stream) {
    const float* sel   = (const float*)d_in[0];
    const float* emb   = (const float*)d_in[1];
    const float* user  = (const float*)d_in[2];
    const float* nrp   = (const float*)d_in[3];
    const int*   attn  = (const int*)d_in[4];
    const int*   refin = (const int*)d_in[5];
    const float* W     = (const float*)d_in[6];
    const float* bal   = (const float*)d_in[7];
    const float* sep   = (const float*)d_in[8];
    const float* orde  = (const float*)d_in[9];

    float* qn  = (float*)d_ws;                       // NB*NH*ND floats (800 KB)
    float* scw = qn + (size_t)NB * NH * ND;          // NB*NH*NS floats (1.6 MB)

    float* out_terms = (float*)d_out;
    float* out_mask  = out_terms + (size_t)NB * ROWS * ND;
    float* out_kid   = out_mask + (size_t)NB * ROWS;

    query_kernel<<<NB * (NH / HB), 256, 0, stream>>>(user, nrp, W, bal, qn);
    score_kernel<<<NB * NH * CHUNKS, 256, 0, stream>>>(sel, qn, scw);
    topk_out_kernel<<<NB * NH, 64, 0, stream>>>(emb, attn, refin, scw, sep, orde,
                                                out_terms, out_mask, out_kid);
}